// Round 7
// baseline (179.073 us; speedup 1.0000x reference)
//
#include <hip/hip_runtime.h>
#include <math.h>

#define EPSF 1e-7f
constexpr int NN  = 100;   // nodes per graph
constexpr int DEG = 99;    // fully-connected: deg = NN-1
constexpr int IN  = 6;
constexpr int H   = 128;
constexpr int G   = 4;     // nodes per block
constexpr float INV_PI = 0.3183098861837907f;

typedef __attribute__((ext_vector_type(8))) short short8;   // 8 bf16
typedef __attribute__((ext_vector_type(4))) float f32x4;

// d_ws layout in short8 units (total 12800 * 16B = 200 KB):
//   [0,512)      : W1 B-fragments
//   [512,6656)   : W2/W3/W4 hi fragments, idx = 512 + ((layer*4+kt)*8+nt)*64 + L
//   [6656,12800) : lo fragments, same indexing + 6144
constexpr int WS_W1 = 0;
constexpr int WS_HI = 512;
constexpr int WS_LO = 6656;

__device__ __forceinline__ float clampf(float x, float lo, float hi) {
    return fminf(fmaxf(x, lo), hi);
}
__device__ __forceinline__ float fast_sig(float x) {
    return __builtin_amdgcn_rcpf(1.f + __expf(-x));
}
__device__ __forceinline__ unsigned short f2bf(float x) {   // RNE fp32->bf16
    unsigned int u = __float_as_uint(x);
    u = (u + 0x7FFFu + ((u >> 16) & 1u)) >> 16;
    return (unsigned short)u;
}
__device__ __forceinline__ float bf2f(unsigned short h) {
    return __uint_as_float(((unsigned int)h) << 16);
}
// fast atan2: octant-reduced minimax poly, ~1e-5 rad
__device__ __forceinline__ float fast_atan2(float y, float x) {
    float ax = fabsf(x), ay = fabsf(y);
    float mx = fmaxf(ax, ay), mn = fminf(ax, ay);
    float r = mn * __builtin_amdgcn_rcpf(fmaxf(mx, 1e-35f));
    float r2 = r * r;
    float p = fmaf(r2, -0.01172120f, 0.05265332f);
    p = fmaf(r2, p, -0.11643287f);
    p = fmaf(r2, p, 0.19354346f);
    p = fmaf(r2, p, -0.33262347f);
    p = fmaf(r2, p, 0.99997726f);
    float t = r * p;
    t = (ay > ax) ? (1.5707963267948966f - t) : t;
    t = (x < 0.f) ? (3.14159265358979323f - t) : t;
    return copysignf(t, y);
}
__device__ __forceinline__ float fast_asin(float z) {
    return fast_atan2(z, sqrtf(fmaxf(0.f, (1.f - z) * (1.f + z))));
}
__device__ __forceinline__ float fast_acos(float z) {
    return fast_atan2(sqrtf(fmaxf(0.f, (1.f - z) * (1.f + z))), z);
}
__device__ __forceinline__ void vel_to_R(float vx, float vy, float vz, float* R) {
    float rho = sqrtf(vx * vx + vy * vy + vz * vz);
    float rxy = sqrtf(vx * vx + vy * vy);
    float inv = __builtin_amdgcn_rcpf(rxy);
    bool big = rxy > 1e-30f;
    float ct = big ? vx * inv : 1.f;
    float st = big ? vy * inv : 0.f;
    float cp = clampf(vz * __builtin_amdgcn_rcpf(rho + EPSF), -1.f, 1.f);
    float sp = sqrtf(fmaxf(0.f, 1.f - cp * cp));
    R[0] = cp * ct; R[1] = -st; R[2] = sp * ct;
    R[3] = cp * st; R[4] = ct;  R[5] = sp * st;
    R[6] = -sp;     R[7] = 0.f; R[8] = cp;
}

// ---------------- Kernel A: weights -> bf16 MFMA fragments in ws
__global__ void conv_w(const float* __restrict__ W1, const float* __restrict__ W2,
                       const float* __restrict__ W3, const float* __restrict__ W4,
                       short8* __restrict__ ws) {
    int t = blockIdx.x * blockDim.x + threadIdx.x;
    if (t >= 104 * 64) return;
    int L = t & 63, f = t >> 6;
    int m = L & 15, qd = L >> 4;
    if (f < 8) {                          // W1 fragments (k<12 live, rest zero)
        int n = f * 16 + m;
        short8 v = 0;
#pragma unroll
        for (int j = 0; j < 8; ++j) {
            int k = qd * 8 + j;
            v[j] = (k < 12) ? (short)f2bf(W1[k * H + n]) : (short)0;
        }
        ws[WS_W1 + f * 64 + L] = v;
    } else {                              // node-MLP weight fragments, hi/lo
        int ff = f - 8;
        int layer = ff >> 5, rest = ff & 31;
        int kt = rest >> 3, nt = rest & 7;
        const float* W = (layer == 0) ? W2 : (layer == 1) ? W3 : W4;
        int n = nt * 16 + m;
        short8 hi = 0, lo = 0;
#pragma unroll
        for (int j = 0; j < 8; ++j) {
            float w = W[(kt * 32 + qd * 8 + j) * H + n];
            unsigned short h = f2bf(w);
            hi[j] = (short)h;
            lo[j] = (short)f2bf(w - bf2f(h));
        }
        int idx = ((layer * 4 + kt) * 8 + nt) * 64 + L;
        ws[WS_HI + idx] = hi;
        ws[WS_LO + idx] = lo;
    }
}

// ---------------- Kernel B: fully fused LoCS layer. One block = 4 nodes.
// Edge features for all 4 nodes computed as one dense 396-job list (2 barriers
// total in the edge phase), then 4 back-to-back MFMA+silu passes. Node MLP:
// writer-side hi/lo bf16 conversion into padded LDS staging; fragments read
// with plain ds_read_b128 (2-way bank aliasing only).
__global__ __launch_bounds__(128)
void locs_fused(const float* __restrict__ in,
                const float* __restrict__ W1, const float* __restrict__ b1,
                const float* __restrict__ b2,
                const float* __restrict__ Wr, const float* __restrict__ br,
                const float* __restrict__ b3, const float* __restrict__ b4,
                const float* __restrict__ W5, const float* __restrict__ b5,
                const short8* __restrict__ wfrag,
                float* __restrict__ out) {
    __shared__ short8 eaA4[G * 7 * 64];          // A fragments, 4 nodes (28 KB)
    __shared__ float baseF[G][H];                // folded silu bias
    __shared__ float xF[G][132];                 // activations (padded stride)
    __shared__ float rmF[G][16];                 // R(9)+cv(3)+pos(3)
    __shared__ float pbF[G][96];
    __shared__ float predF[G][8];
    __shared__ __align__(16) short xbh[544];     // bf16-hi staging, stride 136
    __shared__ __align__(16) short xbl[544];     // bf16-lo staging

    const int tid = threadIdx.x;
    const int L   = tid & 63;
    const int wv  = tid >> 6;
    const int q   = L >> 4;
    const int lm  = L & 15;
    const int bn0 = blockIdx.x * G;
    const int bB  = bn0 / NN;                    // same graph for all 4 (100%4==0)
    const int n0  = bn0 - bB * NN;

    // ---- setup: zero A-fragment arena (pad rows / pad-k stay zero)
    {
        short8 z = 0;
        for (int i = tid; i < G * 7 * 64; i += 128) eaA4[i] = z;
    }
    if (tid < G) {
        const float* xi = in + (bn0 + tid) * IN;
        float R[9];
        vel_to_R(xi[3], xi[4], xi[5], R);
#pragma unroll
        for (int k = 0; k < 9; ++k) rmF[tid][k] = R[k];
        rmF[tid][9]  = R[0] * xi[3] + R[3] * xi[4] + R[6] * xi[5];
        rmF[tid][10] = R[1] * xi[3] + R[4] * xi[4] + R[7] * xi[5];
        rmF[tid][11] = R[2] * xi[3] + R[5] * xi[4] + R[8] * xi[5];
        rmF[tid][12] = xi[0]; rmF[tid][13] = xi[1]; rmF[tid][14] = xi[2];
    }
    __syncthreads();

    // folded silu bias: b1 + cv_g . W1[15..17]
    {
        float w15 = W1[15 * H + tid], w16 = W1[16 * H + tid], w17 = W1[17 * H + tid];
        float b1c = b1[tid];
#pragma unroll
        for (int g = 0; g < G; ++g)
            baseF[g][tid] = b1c + rmF[g][9] * w15 + rmF[g][10] * w16 + rmF[g][11] * w17;
    }
    // W1 B-fragments (this wave's 4 channel-tiles)
    short8 bfr[4];
#pragma unroll
    for (int i = 0; i < 4; ++i) bfr[i] = wfrag[WS_W1 + (wv * 4 + i) * 64 + L];

    // ---- phase 1: ALL 4 nodes' edge features as one dense job list
#pragma unroll
    for (int it = 0; it < 4; ++it) {
        int j = tid + it * 128;
        if (j < G * DEG) {
            int g = (j >= DEG) + (j >= 2 * DEG) + (j >= 3 * DEG);
            int e = j - g * DEG;
            int nG = n0 + g;
            int s = e < nG ? e : e + 1;            // implicit ~eye edge list
            float Rn[9];
#pragma unroll
            for (int k = 0; k < 9; ++k) Rn[k] = rmF[g][k];
            float pix = rmF[g][12], piy = rmF[g][13], piz = rmF[g][14];
            const float* xj = in + (bB * NN + s) * IN;
            float rel0 = xj[0] - pix, rel1 = xj[1] - piy, rel2 = xj[2] - piz;
            float vjx = xj[3], vjy = xj[4], vjz = xj[5];
            float Rs[9];
            vel_to_R(vjx, vjy, vjz, Rs);
            float rr0 = Rn[0] * rel0 + Rn[3] * rel1 + Rn[6] * rel2;
            float rr1 = Rn[1] * rel0 + Rn[4] * rel1 + Rn[7] * rel2;
            float rr2 = Rn[2] * rel0 + Rn[5] * rel1 + Rn[8] * rel2;
            float ro00 = Rn[0] * Rs[0] + Rn[3] * Rs[3] + Rn[6] * Rs[6];
            float ro10 = Rn[1] * Rs[0] + Rn[4] * Rs[3] + Rn[7] * Rs[6];
            float ro20 = Rn[2] * Rs[0] + Rn[5] * Rs[3] + Rn[8] * Rs[6];
            float ro21 = Rn[2] * Rs[1] + Rn[5] * Rs[4] + Rn[8] * Rs[7];
            float ro22 = Rn[2] * Rs[2] + Rn[5] * Rs[5] + Rn[8] * Rs[8];
            float d[12];
            d[0] = rr0; d[1] = rr1; d[2] = rr2;
            d[3] = fast_atan2(ro10, ro00) * INV_PI;
            d[4] = fast_asin(clampf(-ro20, -1.f, 1.f)) * INV_PI;
            d[5] = fast_atan2(ro21, ro22) * INV_PI;
            float dist = sqrtf(rel0 * rel0 + rel1 * rel1 + rel2 * rel2);
            d[6] = dist;                           // |rot_rel| == |rel|
            d[7] = fast_atan2(rr1, rr0);
            d[8] = fast_acos(clampf(rr2 * __builtin_amdgcn_rcpf(dist + EPSF), -1.f, 1.f));
            d[9]  = Rn[0] * vjx + Rn[3] * vjy + Rn[6] * vjz;
            d[10] = Rn[1] * vjx + Rn[4] * vjy + Rn[7] * vjz;
            d[11] = Rn[2] * vjx + Rn[5] * vjy + Rn[8] * vjz;
            short8 lo = 0, hi = 0;
#pragma unroll
            for (int k = 0; k < 8; ++k) lo[k] = (short)f2bf(d[k]);
#pragma unroll
            for (int k = 0; k < 4; ++k) hi[k] = (short)f2bf(d[8 + k]);
            int t = e >> 4, m = e & 15;
            eaA4[g * 448 + t * 64 +      m] = lo;
            eaA4[g * 448 + t * 64 + 16 + m] = hi;
        }
    }
    __syncthreads();

    // ---- phase 2: 4 back-to-back MFMA + silu passes (no barriers between)
#pragma unroll
    for (int g = 0; g < G; ++g) {
        float part[4] = {0.f, 0.f, 0.f, 0.f};
        f32x4 c0, c1, c2, c3;
        {
            float bs0 = baseF[g][wv * 64 +  0 + lm];
            float bs1 = baseF[g][wv * 64 + 16 + lm];
            float bs2 = baseF[g][wv * 64 + 32 + lm];
            float bs3 = baseF[g][wv * 64 + 48 + lm];
            c0 = (f32x4){bs0, bs0, bs0, bs0};
            c1 = (f32x4){bs1, bs1, bs1, bs1};
            c2 = (f32x4){bs2, bs2, bs2, bs2};
            c3 = (f32x4){bs3, bs3, bs3, bs3};
        }
        const short8* ea = eaA4 + g * 448;
#pragma unroll
        for (int t = 0; t < 6; ++t) {
            short8 a = ea[t * 64 + L];
            f32x4 d0 = __builtin_amdgcn_mfma_f32_16x16x32_bf16(a, bfr[0], c0, 0, 0, 0);
            f32x4 d1 = __builtin_amdgcn_mfma_f32_16x16x32_bf16(a, bfr[1], c1, 0, 0, 0);
            f32x4 d2 = __builtin_amdgcn_mfma_f32_16x16x32_bf16(a, bfr[2], c2, 0, 0, 0);
            f32x4 d3 = __builtin_amdgcn_mfma_f32_16x16x32_bf16(a, bfr[3], c3, 0, 0, 0);
#pragma unroll
            for (int r = 0; r < 4; ++r) {
                part[0] += d0[r] * fast_sig(d0[r]);
                part[1] += d1[r] * fast_sig(d1[r]);
                part[2] += d2[r] * fast_sig(d2[r]);
                part[3] += d3[r] * fast_sig(d3[r]);
            }
        }
        {   // tail tile: edges 96..98 live (rows q*4+r with q==0, r<3)
            short8 a = ea[6 * 64 + L];
            f32x4 d0 = __builtin_amdgcn_mfma_f32_16x16x32_bf16(a, bfr[0], c0, 0, 0, 0);
            f32x4 d1 = __builtin_amdgcn_mfma_f32_16x16x32_bf16(a, bfr[1], c1, 0, 0, 0);
            f32x4 d2 = __builtin_amdgcn_mfma_f32_16x16x32_bf16(a, bfr[2], c2, 0, 0, 0);
            f32x4 d3 = __builtin_amdgcn_mfma_f32_16x16x32_bf16(a, bfr[3], c3, 0, 0, 0);
            bool ok = (q == 0);
#pragma unroll
            for (int r = 0; r < 3; ++r) {
                part[0] += ok ? d0[r] * fast_sig(d0[r]) : 0.f;
                part[1] += ok ? d1[r] * fast_sig(d1[r]) : 0.f;
                part[2] += ok ? d2[r] * fast_sig(d2[r]) : 0.f;
                part[3] += ok ? d3[r] * fast_sig(d3[r]) : 0.f;
            }
        }
#pragma unroll
        for (int i = 0; i < 4; ++i) {
            float v = part[i];
            v += __shfl_xor(v, 16, 64);
            v += __shfl_xor(v, 32, 64);
            if (L < 16) xF[g][wv * 64 + i * 16 + L] = v;
        }
    }
    __syncthreads();

    // ---- node MLP: 3 layers, writer-side hi/lo bf16 conversion + MFMA
#pragma unroll
    for (int layer = 0; layer < 3; ++layer) {
        // conversion: all threads, 4 elems each -> padded bf16 staging
#pragma unroll
        for (int r = 0; r < G; ++r) {
            float v = xF[r][tid];
            unsigned short hh = f2bf(v);
            xbh[r * 136 + tid] = (short)hh;
            xbl[r * 136 + tid] = (short)f2bf(v - bf2f(hh));
        }
        __syncthreads();
        int rowb = (lm & 3) * 136;                 // rows 4..15 read dup rows (unread D rows)
        short8 ah[4], al[4];
#pragma unroll
        for (int kt = 0; kt < 4; ++kt) {
            ah[kt] = *(const short8*)&xbh[rowb + kt * 32 + q * 8];
            al[kt] = *(const short8*)&xbl[rowb + kt * 32 + q * 8];
        }
        f32x4 acc[4];
#pragma unroll
        for (int i = 0; i < 4; ++i) acc[i] = (f32x4){0.f, 0.f, 0.f, 0.f};
#pragma unroll
        for (int kt = 0; kt < 4; ++kt) {
            int base = ((layer * 4 + kt) * 8 + wv * 4) * 64 + L;
#pragma unroll
            for (int i = 0; i < 4; ++i) {
                short8 bh = wfrag[WS_HI + base + i * 64];
                short8 bl = wfrag[WS_LO + base + i * 64];
                acc[i] = __builtin_amdgcn_mfma_f32_16x16x32_bf16(ah[kt], bh, acc[i], 0, 0, 0);
                acc[i] = __builtin_amdgcn_mfma_f32_16x16x32_bf16(al[kt], bh, acc[i], 0, 0, 0);
                acc[i] = __builtin_amdgcn_mfma_f32_16x16x32_bf16(ah[kt], bl, acc[i], 0, 0, 0);
            }
        }
        if (L < 16) {                  // quad 0 holds rows 0..3 (the 4 nodes)
#pragma unroll
            for (int i = 0; i < 4; ++i) {
                int ch = wv * 64 + i * 16 + lm;
                if (layer == 0) {
                    float b2c = b2[ch], brc = br[ch];
                    float w3c = Wr[3 * H + ch], w4c = Wr[4 * H + ch], w5c = Wr[5 * H + ch];
#pragma unroll
                    for (int r = 0; r < 4; ++r)
                        xF[r][ch] = acc[i][r] * (1.f / 99.f) + b2c
                                  + rmF[r][9] * w3c + rmF[r][10] * w4c
                                  + rmF[r][11] * w5c + brc;
                } else {
                    float bb = (layer == 1) ? b3[ch] : b4[ch];
#pragma unroll
                    for (int r = 0; r < 4; ++r)
                        xF[r][ch] = fmaxf(0.f, acc[i][r] + bb);
                }
            }
        }
        __syncthreads();               // xF writes visible to next conversion
    }

    // ---- pred = p2 @ W5 + b5, then rotate + residual
    if (tid < 96) {
        int o = tid >> 4, sl = tid & 15, kb = sl * 8;
        float w5[8];
#pragma unroll
        for (int j = 0; j < 8; ++j) w5[j] = W5[(kb + j) * IN + o];
#pragma unroll
        for (int g = 0; g < G; ++g) {
            float s = 0.f;
#pragma unroll
            for (int j = 0; j < 8; ++j) s = fmaf(xF[g][kb + j], w5[j], s);
            pbF[g][sl * 6 + o] = s;
        }
    }
    __syncthreads();
    if (tid < 24) {
        int g = tid / 6, o = tid - g * 6;
        float s = b5[o];
#pragma unroll
        for (int sl = 0; sl < 16; ++sl) s += pbF[g][sl * 6 + o];
        predF[g][o] = s;
    }
    __syncthreads();
    if (tid < 24) {
        int g = tid / 6, o = tid - g * 6;
        int r = (o < 3) ? o : o - 3;
        int off = (o < 3) ? 0 : 3;
        float gl = rmF[g][r * 3 + 0] * predF[g][off + 0]
                 + rmF[g][r * 3 + 1] * predF[g][off + 1]
                 + rmF[g][r * 3 + 2] * predF[g][off + 2];
        int bng = bn0 + g;
        out[bng * IN + o] = in[bng * IN + o] + gl;
    }
}

extern "C" void kernel_launch(void* const* d_in, const int* in_sizes, int n_in,
                              void* d_out, int out_size, void* d_ws, size_t ws_size,
                              hipStream_t stream) {
    const float* in = (const float*)d_in[0];
    const float* W1 = (const float*)d_in[1];
    const float* b1 = (const float*)d_in[2];
    const float* W2 = (const float*)d_in[3];
    const float* b2 = (const float*)d_in[4];
    const float* Wr = (const float*)d_in[5];
    const float* br = (const float*)d_in[6];
    const float* W3 = (const float*)d_in[7];
    const float* b3 = (const float*)d_in[8];
    const float* W4 = (const float*)d_in[9];
    const float* b4 = (const float*)d_in[10];
    const float* W5 = (const float*)d_in[11];
    const float* b5 = (const float*)d_in[12];
    float* out = (float*)d_out;

    short8* wsF = (short8*)d_ws;       // 200 KB of fragments

    const int BN = in_sizes[0] / IN;   // B*N = 12800
    conv_w<<<26, 256, 0, stream>>>(W1, W2, W3, W4, wsF);
    locs_fused<<<BN / G, 128, 0, stream>>>(in, W1, b1, b2, Wr, br, b3, b4,
                                           W5, b5, wsF, out);
}

// Round 8
// 161.615 us; speedup vs baseline: 1.1080x; 1.1080x over previous
//
#include <hip/hip_runtime.h>
#include <math.h>

#define EPSF 1e-7f
constexpr int NN  = 100;   // nodes per graph
constexpr int DEG = 99;    // fully-connected: deg = NN-1
constexpr int IN  = 6;
constexpr int H   = 128;
constexpr int G   = 4;     // nodes per block
constexpr float INV_PI = 0.3183098861837907f;

typedef __attribute__((ext_vector_type(8))) short short8;   // 8 bf16
typedef __attribute__((ext_vector_type(4))) float f32x4;

// d_ws layout in short8 units (total 12800 * 16B = 200 KB):
//   [0,512)      : W1 B-fragments
//   [512,6656)   : W2/W3/W4 hi fragments, idx = 512 + ((layer*4+kt)*8+nt)*64 + L
//   [6656,12800) : lo fragments, same indexing + 6144
constexpr int WS_W1 = 0;
constexpr int WS_HI = 512;
constexpr int WS_LO = 6656;

constexpr int XST = 144;   // bf16 staging stride (288B: 16B-aligned rows, <=2-way banks)

__device__ __forceinline__ float clampf(float x, float lo, float hi) {
    return fminf(fmaxf(x, lo), hi);
}
__device__ __forceinline__ float fast_sig(float x) {
    return __builtin_amdgcn_rcpf(1.f + __expf(-x));
}
__device__ __forceinline__ unsigned short f2bf(float x) {   // RNE fp32->bf16
    unsigned int u = __float_as_uint(x);
    u = (u + 0x7FFFu + ((u >> 16) & 1u)) >> 16;
    return (unsigned short)u;
}
__device__ __forceinline__ float bf2f(unsigned short h) {
    return __uint_as_float(((unsigned int)h) << 16);
}
// fast atan2: octant-reduced minimax poly, ~1e-5 rad
__device__ __forceinline__ float fast_atan2(float y, float x) {
    float ax = fabsf(x), ay = fabsf(y);
    float mx = fmaxf(ax, ay), mn = fminf(ax, ay);
    float r = mn * __builtin_amdgcn_rcpf(fmaxf(mx, 1e-35f));
    float r2 = r * r;
    float p = fmaf(r2, -0.01172120f, 0.05265332f);
    p = fmaf(r2, p, -0.11643287f);
    p = fmaf(r2, p, 0.19354346f);
    p = fmaf(r2, p, -0.33262347f);
    p = fmaf(r2, p, 0.99997726f);
    float t = r * p;
    t = (ay > ax) ? (1.5707963267948966f - t) : t;
    t = (x < 0.f) ? (3.14159265358979323f - t) : t;
    return copysignf(t, y);
}
__device__ __forceinline__ float fast_asin(float z) {
    return fast_atan2(z, sqrtf(fmaxf(0.f, (1.f - z) * (1.f + z))));
}
__device__ __forceinline__ float fast_acos(float z) {
    return fast_atan2(sqrtf(fmaxf(0.f, (1.f - z) * (1.f + z))), z);
}
__device__ __forceinline__ void vel_to_R(float vx, float vy, float vz, float* R) {
    float rho = sqrtf(vx * vx + vy * vy + vz * vz);
    float rxy = sqrtf(vx * vx + vy * vy);
    float inv = __builtin_amdgcn_rcpf(rxy);
    bool big = rxy > 1e-30f;
    float ct = big ? vx * inv : 1.f;
    float st = big ? vy * inv : 0.f;
    float cp = clampf(vz * __builtin_amdgcn_rcpf(rho + EPSF), -1.f, 1.f);
    float sp = sqrtf(fmaxf(0.f, 1.f - cp * cp));
    R[0] = cp * ct; R[1] = -st; R[2] = sp * ct;
    R[3] = cp * st; R[4] = ct;  R[5] = sp * st;
    R[6] = -sp;     R[7] = 0.f; R[8] = cp;
}

// ---------------- Kernel A: weights -> bf16 MFMA fragments in ws
__global__ void conv_w(const float* __restrict__ W1, const float* __restrict__ W2,
                       const float* __restrict__ W3, const float* __restrict__ W4,
                       short8* __restrict__ ws) {
    int t = blockIdx.x * blockDim.x + threadIdx.x;
    if (t >= 104 * 64) return;
    int L = t & 63, f = t >> 6;
    int m = L & 15, qd = L >> 4;
    if (f < 8) {                          // W1 fragments (k<12 live, rest zero)
        int n = f * 16 + m;
        short8 v = 0;
#pragma unroll
        for (int j = 0; j < 8; ++j) {
            int k = qd * 8 + j;
            v[j] = (k < 12) ? (short)f2bf(W1[k * H + n]) : (short)0;
        }
        ws[WS_W1 + f * 64 + L] = v;
    } else {                              // node-MLP weight fragments, hi/lo
        int ff = f - 8;
        int layer = ff >> 5, rest = ff & 31;
        int kt = rest >> 3, nt = rest & 7;
        const float* W = (layer == 0) ? W2 : (layer == 1) ? W3 : W4;
        int n = nt * 16 + m;
        short8 hi = 0, lo = 0;
#pragma unroll
        for (int j = 0; j < 8; ++j) {
            float w = W[(kt * 32 + qd * 8 + j) * H + n];
            unsigned short h = f2bf(w);
            hi[j] = (short)h;
            lo[j] = (short)f2bf(w - bf2f(h));
        }
        int idx = ((layer * 4 + kt) * 8 + nt) * 64 + L;
        ws[WS_HI + idx] = hi;
        ws[WS_LO + idx] = lo;
    }
}

// ---------------- Kernel B: fully fused LoCS layer. One block = 4 nodes.
// Edge phase SOFTWARE-PIPELINED with a 2-deep A-fragment arena: each barrier
// interval issues MFMA+silu for node g AND edge-feature compute for node g+1
// (independent streams -> VALU/trans/MFMA ports co-scheduled). Node MLP via
// hi/lo bf16 MFMA with writer-side conversion into padded LDS staging.
__global__ __launch_bounds__(128)
void locs_fused(const float* __restrict__ in,
                const float* __restrict__ W1, const float* __restrict__ b1,
                const float* __restrict__ b2,
                const float* __restrict__ Wr, const float* __restrict__ br,
                const float* __restrict__ b3, const float* __restrict__ b4,
                const float* __restrict__ W5, const float* __restrict__ b5,
                const short8* __restrict__ wfrag,
                float* __restrict__ out) {
    __shared__ short8 eaA[2][7 * 64];    // double-buffered A arena (2 x 3.5 KB)
    __shared__ float baseF[G][H];        // folded silu bias
    __shared__ float xF[G][132];         // activations (padded stride)
    __shared__ float rmF[G][16];         // R(9)+cv(3)+pos(3)
    __shared__ float pbF[G][96];
    __shared__ float predF[G][8];
    __shared__ __align__(16) short xbh[G * XST];   // bf16-hi staging
    __shared__ __align__(16) short xbl[G * XST];   // bf16-lo staging

    const int tid = threadIdx.x;
    const int L   = tid & 63;
    const int wv  = tid >> 6;
    const int q   = L >> 4;
    const int lm  = L & 15;
    const int bn0 = blockIdx.x * G;
    const int bB  = bn0 / NN;            // same graph for all 4 (100 % 4 == 0)
    const int n0  = bn0 - bB * NN;

    // ---- setup: zero both arenas (pad rows / pad-k stay zero forever)
    {
        short8 z = 0;
        for (int i = tid; i < 2 * 7 * 64; i += 128) eaA[0][i] = z;
    }
    if (tid < G) {
        const float* xi = in + (bn0 + tid) * IN;
        float R[9];
        vel_to_R(xi[3], xi[4], xi[5], R);
#pragma unroll
        for (int k = 0; k < 9; ++k) rmF[tid][k] = R[k];
        rmF[tid][9]  = R[0] * xi[3] + R[3] * xi[4] + R[6] * xi[5];
        rmF[tid][10] = R[1] * xi[3] + R[4] * xi[4] + R[7] * xi[5];
        rmF[tid][11] = R[2] * xi[3] + R[5] * xi[4] + R[8] * xi[5];
        rmF[tid][12] = xi[0]; rmF[tid][13] = xi[1]; rmF[tid][14] = xi[2];
    }
    __syncthreads();

    // folded silu bias: b1 + cv_g . W1[15..17]
    {
        float w15 = W1[15 * H + tid], w16 = W1[16 * H + tid], w17 = W1[17 * H + tid];
        float b1c = b1[tid];
#pragma unroll
        for (int g = 0; g < G; ++g)
            baseF[g][tid] = b1c + rmF[g][9] * w15 + rmF[g][10] * w16 + rmF[g][11] * w17;
    }
    // W1 B-fragments (this wave's 4 channel-tiles)
    short8 bfr[4];
#pragma unroll
    for (int i = 0; i < 4; ++i) bfr[i] = wfrag[WS_W1 + (wv * 4 + i) * 64 + L];

    // edge-feature producer for node g -> arena buf
    auto edge_features = [&](int g, int buf) {
        if (tid < DEG) {
            int nG = n0 + g;
            int s = tid < nG ? tid : tid + 1;        // implicit ~eye edge list
            float Rn[9];
#pragma unroll
            for (int k = 0; k < 9; ++k) Rn[k] = rmF[g][k];
            float pix = rmF[g][12], piy = rmF[g][13], piz = rmF[g][14];
            const float* xj = in + (bB * NN + s) * IN;
            float rel0 = xj[0] - pix, rel1 = xj[1] - piy, rel2 = xj[2] - piz;
            float vjx = xj[3], vjy = xj[4], vjz = xj[5];
            float Rs[9];
            vel_to_R(vjx, vjy, vjz, Rs);
            float rr0 = Rn[0] * rel0 + Rn[3] * rel1 + Rn[6] * rel2;
            float rr1 = Rn[1] * rel0 + Rn[4] * rel1 + Rn[7] * rel2;
            float rr2 = Rn[2] * rel0 + Rn[5] * rel1 + Rn[8] * rel2;
            float ro00 = Rn[0] * Rs[0] + Rn[3] * Rs[3] + Rn[6] * Rs[6];
            float ro10 = Rn[1] * Rs[0] + Rn[4] * Rs[3] + Rn[7] * Rs[6];
            float ro20 = Rn[2] * Rs[0] + Rn[5] * Rs[3] + Rn[8] * Rs[6];
            float ro21 = Rn[2] * Rs[1] + Rn[5] * Rs[4] + Rn[8] * Rs[7];
            float ro22 = Rn[2] * Rs[2] + Rn[5] * Rs[5] + Rn[8] * Rs[8];
            float d[12];
            d[0] = rr0; d[1] = rr1; d[2] = rr2;
            d[3] = fast_atan2(ro10, ro00) * INV_PI;
            d[4] = fast_asin(clampf(-ro20, -1.f, 1.f)) * INV_PI;
            d[5] = fast_atan2(ro21, ro22) * INV_PI;
            float dist = sqrtf(rel0 * rel0 + rel1 * rel1 + rel2 * rel2);
            d[6] = dist;                             // |rot_rel| == |rel|
            d[7] = fast_atan2(rr1, rr0);
            d[8] = fast_acos(clampf(rr2 * __builtin_amdgcn_rcpf(dist + EPSF), -1.f, 1.f));
            d[9]  = Rn[0] * vjx + Rn[3] * vjy + Rn[6] * vjz;
            d[10] = Rn[1] * vjx + Rn[4] * vjy + Rn[7] * vjz;
            d[11] = Rn[2] * vjx + Rn[5] * vjy + Rn[8] * vjz;
            short8 lo = 0, hi = 0;
#pragma unroll
            for (int k = 0; k < 8; ++k) lo[k] = (short)f2bf(d[k]);
#pragma unroll
            for (int k = 0; k < 4; ++k) hi[k] = (short)f2bf(d[8 + k]);
            int t = tid >> 4, m = tid & 15;
            eaA[buf][t * 64 +      m] = lo;
            eaA[buf][t * 64 + 16 + m] = hi;
        }
    };

    // ---- pipelined edge phase: prologue fills arena 0
    edge_features(0, 0);
    __syncthreads();

#pragma unroll
    for (int g = 0; g < G; ++g) {
        // consumer: MFMA + silu + row-accumulate on arena g&1
        float part[4] = {0.f, 0.f, 0.f, 0.f};
        f32x4 c0, c1, c2, c3;
        {
            float bs0 = baseF[g][wv * 64 +  0 + lm];
            float bs1 = baseF[g][wv * 64 + 16 + lm];
            float bs2 = baseF[g][wv * 64 + 32 + lm];
            float bs3 = baseF[g][wv * 64 + 48 + lm];
            c0 = (f32x4){bs0, bs0, bs0, bs0};
            c1 = (f32x4){bs1, bs1, bs1, bs1};
            c2 = (f32x4){bs2, bs2, bs2, bs2};
            c3 = (f32x4){bs3, bs3, bs3, bs3};
        }
        const short8* ea = eaA[g & 1];
#pragma unroll
        for (int t = 0; t < 6; ++t) {
            short8 a = ea[t * 64 + L];
            f32x4 d0 = __builtin_amdgcn_mfma_f32_16x16x32_bf16(a, bfr[0], c0, 0, 0, 0);
            f32x4 d1 = __builtin_amdgcn_mfma_f32_16x16x32_bf16(a, bfr[1], c1, 0, 0, 0);
            f32x4 d2 = __builtin_amdgcn_mfma_f32_16x16x32_bf16(a, bfr[2], c2, 0, 0, 0);
            f32x4 d3 = __builtin_amdgcn_mfma_f32_16x16x32_bf16(a, bfr[3], c3, 0, 0, 0);
#pragma unroll
            for (int r = 0; r < 4; ++r) {
                part[0] += d0[r] * fast_sig(d0[r]);
                part[1] += d1[r] * fast_sig(d1[r]);
                part[2] += d2[r] * fast_sig(d2[r]);
                part[3] += d3[r] * fast_sig(d3[r]);
            }
        }
        {   // tail tile: edges 96..98 live (q==0, r<3)
            short8 a = ea[6 * 64 + L];
            f32x4 d0 = __builtin_amdgcn_mfma_f32_16x16x32_bf16(a, bfr[0], c0, 0, 0, 0);
            f32x4 d1 = __builtin_amdgcn_mfma_f32_16x16x32_bf16(a, bfr[1], c1, 0, 0, 0);
            f32x4 d2 = __builtin_amdgcn_mfma_f32_16x16x32_bf16(a, bfr[2], c2, 0, 0, 0);
            f32x4 d3 = __builtin_amdgcn_mfma_f32_16x16x32_bf16(a, bfr[3], c3, 0, 0, 0);
            bool ok = (q == 0);
#pragma unroll
            for (int r = 0; r < 3; ++r) {
                part[0] += ok ? d0[r] * fast_sig(d0[r]) : 0.f;
                part[1] += ok ? d1[r] * fast_sig(d1[r]) : 0.f;
                part[2] += ok ? d2[r] * fast_sig(d2[r]) : 0.f;
                part[3] += ok ? d3[r] * fast_sig(d3[r]) : 0.f;
            }
        }
        // producer: features for node g+1 into the other arena (overlapped issue)
        if (g < G - 1) edge_features(g + 1, (g + 1) & 1);
        // reduce over the 4 q-groups
#pragma unroll
        for (int i = 0; i < 4; ++i) {
            float v = part[i];
            v += __shfl_xor(v, 16, 64);
            v += __shfl_xor(v, 32, 64);
            if (L < 16) xF[g][wv * 64 + i * 16 + L] = v;
        }
        __syncthreads();
    }

    // ---- node MLP: 3 layers, writer-side hi/lo bf16 conversion + MFMA
#pragma unroll
    for (int layer = 0; layer < 3; ++layer) {
#pragma unroll
        for (int r = 0; r < G; ++r) {
            float v = xF[r][tid];
            unsigned short hh = f2bf(v);
            xbh[r * XST + tid] = (short)hh;
            xbl[r * XST + tid] = (short)f2bf(v - bf2f(hh));
        }
        __syncthreads();
        int rowb = (lm & 3) * XST;       // rows 4..15 read dup rows (unread D rows)
        short8 ah[4], al[4];
#pragma unroll
        for (int kt = 0; kt < 4; ++kt) {
            ah[kt] = *(const short8*)&xbh[rowb + kt * 32 + q * 8];
            al[kt] = *(const short8*)&xbl[rowb + kt * 32 + q * 8];
        }
        f32x4 acc[4];
#pragma unroll
        for (int i = 0; i < 4; ++i) acc[i] = (f32x4){0.f, 0.f, 0.f, 0.f};
#pragma unroll
        for (int kt = 0; kt < 4; ++kt) {
            int base = ((layer * 4 + kt) * 8 + wv * 4) * 64 + L;
#pragma unroll
            for (int i = 0; i < 4; ++i) {
                short8 bh = wfrag[WS_HI + base + i * 64];
                short8 bl = wfrag[WS_LO + base + i * 64];
                acc[i] = __builtin_amdgcn_mfma_f32_16x16x32_bf16(ah[kt], bh, acc[i], 0, 0, 0);
                acc[i] = __builtin_amdgcn_mfma_f32_16x16x32_bf16(al[kt], bh, acc[i], 0, 0, 0);
                acc[i] = __builtin_amdgcn_mfma_f32_16x16x32_bf16(ah[kt], bl, acc[i], 0, 0, 0);
            }
        }
        __syncthreads();                 // xbh/xbl reads done; xF safe to write
        if (L < 16) {                    // quad 0 holds rows 0..3 (the 4 nodes)
#pragma unroll
            for (int i = 0; i < 4; ++i) {
                int ch = wv * 64 + i * 16 + lm;
                if (layer == 0) {
                    float b2c = b2[ch], brc = br[ch];
                    float w3c = Wr[3 * H + ch], w4c = Wr[4 * H + ch], w5c = Wr[5 * H + ch];
#pragma unroll
                    for (int r = 0; r < 4; ++r)
                        xF[r][ch] = acc[i][r] * (1.f / 99.f) + b2c
                                  + rmF[r][9] * w3c + rmF[r][10] * w4c
                                  + rmF[r][11] * w5c + brc;
                } else {
                    float bb = (layer == 1) ? b3[ch] : b4[ch];
#pragma unroll
                    for (int r = 0; r < 4; ++r)
                        xF[r][ch] = fmaxf(0.f, acc[i][r] + bb);
                }
            }
        }
        __syncthreads();
    }

    // ---- pred = p2 @ W5 + b5, then rotate + residual
    if (tid < 96) {
        int o = tid >> 4, sl = tid & 15, kb = sl * 8;
        float w5[8];
#pragma unroll
        for (int j = 0; j < 8; ++j) w5[j] = W5[(kb + j) * IN + o];
#pragma unroll
        for (int g = 0; g < G; ++g) {
            float s = 0.f;
#pragma unroll
            for (int j = 0; j < 8; ++j) s = fmaf(xF[g][kb + j], w5[j], s);
            pbF[g][sl * 6 + o] = s;
        }
    }
    __syncthreads();
    if (tid < 24) {
        int g = tid / 6, o = tid - g * 6;
        float s = b5[o];
#pragma unroll
        for (int sl = 0; sl < 16; ++sl) s += pbF[g][sl * 6 + o];
        predF[g][o] = s;
    }
    __syncthreads();
    if (tid < 24) {
        int g = tid / 6, o = tid - g * 6;
        int r = (o < 3) ? o : o - 3;
        int off = (o < 3) ? 0 : 3;
        float gl = rmF[g][r * 3 + 0] * predF[g][off + 0]
                 + rmF[g][r * 3 + 1] * predF[g][off + 1]
                 + rmF[g][r * 3 + 2] * predF[g][off + 2];
        int bng = bn0 + g;
        out[bng * IN + o] = in[bng * IN + o] + gl;
    }
}

extern "C" void kernel_launch(void* const* d_in, const int* in_sizes, int n_in,
                              void* d_out, int out_size, void* d_ws, size_t ws_size,
                              hipStream_t stream) {
    const float* in = (const float*)d_in[0];
    const float* W1 = (const float*)d_in[1];
    const float* b1 = (const float*)d_in[2];
    const float* W2 = (const float*)d_in[3];
    const float* b2 = (const float*)d_in[4];
    const float* Wr = (const float*)d_in[5];
    const float* br = (const float*)d_in[6];
    const float* W3 = (const float*)d_in[7];
    const float* b3 = (const float*)d_in[8];
    const float* W4 = (const float*)d_in[9];
    const float* b4 = (const float*)d_in[10];
    const float* W5 = (const float*)d_in[11];
    const float* b5 = (const float*)d_in[12];
    float* out = (float*)d_out;

    short8* wsF = (short8*)d_ws;       // 200 KB of fragments

    const int BN = in_sizes[0] / IN;   // B*N = 12800
    conv_w<<<26, 256, 0, stream>>>(W1, W2, W3, W4, wsF);
    locs_fused<<<BN / G, 128, 0, stream>>>(in, W1, b1, b2, Wr, br, b3, b4,
                                           W5, b5, wsF, out);
}

// Round 9
// 147.154 us; speedup vs baseline: 1.2169x; 1.0983x over previous
//
#include <hip/hip_runtime.h>
#include <math.h>

#define EPSF 1e-7f
constexpr int NN  = 100;   // nodes per graph
constexpr int DEG = 99;    // fully-connected: deg = NN-1
constexpr int IN  = 6;
constexpr int H   = 128;
constexpr int G   = 4;     // nodes per block
constexpr float INV_PI = 0.3183098861837907f;

typedef __attribute__((ext_vector_type(4))) _Float16 half4;
typedef __attribute__((ext_vector_type(8))) _Float16 half8;
typedef __attribute__((ext_vector_type(4))) float f32x4;

constexpr int XST = 144;   // fp16 staging stride (288B rows: 16B-aligned)

__device__ __forceinline__ float clampf(float x, float lo, float hi) {
    return fminf(fmaxf(x, lo), hi);
}
__device__ __forceinline__ float fast_sig(float x) {
    return __builtin_amdgcn_rcpf(1.f + __expf(-x));
}
// fast atan2: octant-reduced minimax poly, ~1e-5 rad
__device__ __forceinline__ float fast_atan2(float y, float x) {
    float ax = fabsf(x), ay = fabsf(y);
    float mx = fmaxf(ax, ay), mn = fminf(ax, ay);
    float r = mn * __builtin_amdgcn_rcpf(fmaxf(mx, 1e-35f));
    float r2 = r * r;
    float p = fmaf(r2, -0.01172120f, 0.05265332f);
    p = fmaf(r2, p, -0.11643287f);
    p = fmaf(r2, p, 0.19354346f);
    p = fmaf(r2, p, -0.33262347f);
    p = fmaf(r2, p, 0.99997726f);
    float t = r * p;
    t = (ay > ax) ? (1.5707963267948966f - t) : t;
    t = (x < 0.f) ? (3.14159265358979323f - t) : t;
    return copysignf(t, y);
}
__device__ __forceinline__ float fast_asin(float z) {
    return fast_atan2(z, sqrtf(fmaxf(0.f, (1.f - z) * (1.f + z))));
}
__device__ __forceinline__ float fast_acos(float z) {
    return fast_atan2(sqrtf(fmaxf(0.f, (1.f - z) * (1.f + z))), z);
}
__device__ __forceinline__ void vel_to_R(float vx, float vy, float vz, float* R) {
    float rho = sqrtf(vx * vx + vy * vy + vz * vz);
    float rxy = sqrtf(vx * vx + vy * vy);
    float inv = __builtin_amdgcn_rcpf(rxy);
    bool big = rxy > 1e-30f;
    float ct = big ? vx * inv : 1.f;
    float st = big ? vy * inv : 0.f;
    float cp = clampf(vz * __builtin_amdgcn_rcpf(rho + EPSF), -1.f, 1.f);
    float sp = sqrtf(fmaxf(0.f, 1.f - cp * cp));
    R[0] = cp * ct; R[1] = -st; R[2] = sp * ct;
    R[3] = cp * st; R[4] = ct;  R[5] = sp * st;
    R[6] = -sp;     R[7] = 0.f; R[8] = cp;
}

// ---------------- Kernel A: weights -> fp16 MFMA fragments in ws.
//   w1f  : 8 tiles x 64 lanes, half4 (K=16 layout, k<12 live)   [4 KB]
//   wmlp : W2/W3/W4, 3 layers x 4 kt x 8 nt x 64 lanes, half8   [96 KB]
__global__ void conv_w(const float* __restrict__ W1, const float* __restrict__ W2,
                       const float* __restrict__ W3, const float* __restrict__ W4,
                       half4* __restrict__ w1f, half8* __restrict__ wmlp) {
    int t = blockIdx.x * blockDim.x + threadIdx.x;
    if (t >= 104 * 64) return;
    int L = t & 63, f = t >> 6;
    int m = L & 15, qd = L >> 4;
    if (f < 8) {                          // W1 fragments (K=16, k<12 live)
        int n = f * 16 + m;
        half4 v;
#pragma unroll
        for (int j = 0; j < 4; ++j) {
            int k = qd * 4 + j;
            v[j] = (k < 12) ? (_Float16)W1[k * H + n] : (_Float16)0.f;
        }
        w1f[f * 64 + L] = v;
    } else {                              // node-MLP weight fragments (K=32)
        int ff = f - 8;
        int layer = ff >> 5, rest = ff & 31;
        int kt = rest >> 3, nt = rest & 7;
        const float* W = (layer == 0) ? W2 : (layer == 1) ? W3 : W4;
        int n = nt * 16 + m;
        half8 v;
#pragma unroll
        for (int j = 0; j < 8; ++j)
            v[j] = (_Float16)W[(kt * 32 + qd * 8 + j) * H + n];
        wmlp[((layer * 4 + kt) * 8 + nt) * 64 + L] = v;
    }
}

// ---------------- Kernel B: fully fused LoCS layer. One block = 4 nodes.
// Edge phase software-pipelined (2-deep fp16 A arena, K=16 MFMA). Node MLP in
// single fp16 via 16x16x32 MFMA. Float scratch in ONE typed pool (TBAA-safe);
// epilogue buffers alias the dead baseF region.
__global__ __launch_bounds__(128, 6)
void locs_fused(const float* __restrict__ in,
                const float* __restrict__ W1, const float* __restrict__ b1,
                const float* __restrict__ b2,
                const float* __restrict__ Wr, const float* __restrict__ br,
                const float* __restrict__ b3, const float* __restrict__ b4,
                const float* __restrict__ W5, const float* __restrict__ b5,
                const half4* __restrict__ w1f, const half8* __restrict__ wmlp,
                float* __restrict__ out) {
    __shared__ half4 eaA[2 * 7 * 64];            // A arena (2 x 3.5 KB)
    __shared__ float poolF[1104];                // baseF/pb/pred | xF | rmF
    __shared__ _Float16 xh[G * XST];             // fp16 activation staging

    float* baseF = poolF;                        // [4][128] (dead after edge phase)
    float* xFp   = poolF + 512;                  // [4][132]
    float* rmFp  = poolF + 1040;                 // [4][16]
    float* pbF   = poolF;                        // alias: [4][96]
    float* predF = poolF + 384;                  // alias: [4][8]

    const int tid = threadIdx.x;
    const int L   = tid & 63;
    const int wv  = tid >> 6;
    const int q   = L >> 4;
    const int lm  = L & 15;
    const int bn0 = blockIdx.x * G;
    const int bB  = bn0 / NN;                    // same graph for all 4 nodes
    const int n0  = bn0 - bB * NN;

    // ---- setup: zero arenas (pad rows / pad-k stay zero all launch)
    {
        half4 z = {0, 0, 0, 0};
#pragma unroll
        for (int i = 0; i < 7; ++i) eaA[tid + i * 128] = z;
    }
    if (tid < G) {
        const float* xi = in + (bn0 + tid) * IN;
        float R[9];
        vel_to_R(xi[3], xi[4], xi[5], R);
#pragma unroll
        for (int k = 0; k < 9; ++k) rmFp[tid * 16 + k] = R[k];
        rmFp[tid * 16 + 9]  = R[0] * xi[3] + R[3] * xi[4] + R[6] * xi[5];
        rmFp[tid * 16 + 10] = R[1] * xi[3] + R[4] * xi[4] + R[7] * xi[5];
        rmFp[tid * 16 + 11] = R[2] * xi[3] + R[5] * xi[4] + R[8] * xi[5];
        rmFp[tid * 16 + 12] = xi[0];
        rmFp[tid * 16 + 13] = xi[1];
        rmFp[tid * 16 + 14] = xi[2];
    }
    __syncthreads();

    // folded silu bias: b1 + cv_g . W1[15..17]
    {
        float w15 = W1[15 * H + tid], w16 = W1[16 * H + tid], w17 = W1[17 * H + tid];
        float b1c = b1[tid];
#pragma unroll
        for (int g = 0; g < G; ++g)
            baseF[g * 128 + tid] = b1c + rmFp[g * 16 + 9] * w15
                                 + rmFp[g * 16 + 10] * w16 + rmFp[g * 16 + 11] * w17;
    }
    // W1 B-fragments (this wave's 4 channel-tiles)
    half4 bfr[4];
#pragma unroll
    for (int i = 0; i < 4; ++i) bfr[i] = w1f[(wv * 4 + i) * 64 + L];

    // edge-feature producer for node g -> arena buf
    auto edge_features = [&](int g, int buf) {
        if (tid < DEG) {
            int nG = n0 + g;
            int s = tid < nG ? tid : tid + 1;     // implicit ~eye edge list
            float Rn[9];
#pragma unroll
            for (int k = 0; k < 9; ++k) Rn[k] = rmFp[g * 16 + k];
            float pix = rmFp[g * 16 + 12], piy = rmFp[g * 16 + 13], piz = rmFp[g * 16 + 14];
            const float* xj = in + (bB * NN + s) * IN;
            float rel0 = xj[0] - pix, rel1 = xj[1] - piy, rel2 = xj[2] - piz;
            float vjx = xj[3], vjy = xj[4], vjz = xj[5];
            float Rs[9];
            vel_to_R(vjx, vjy, vjz, Rs);
            float rr0 = Rn[0] * rel0 + Rn[3] * rel1 + Rn[6] * rel2;
            float rr1 = Rn[1] * rel0 + Rn[4] * rel1 + Rn[7] * rel2;
            float rr2 = Rn[2] * rel0 + Rn[5] * rel1 + Rn[8] * rel2;
            float ro00 = Rn[0] * Rs[0] + Rn[3] * Rs[3] + Rn[6] * Rs[6];
            float ro10 = Rn[1] * Rs[0] + Rn[4] * Rs[3] + Rn[7] * Rs[6];
            float ro20 = Rn[2] * Rs[0] + Rn[5] * Rs[3] + Rn[8] * Rs[6];
            float ro21 = Rn[2] * Rs[1] + Rn[5] * Rs[4] + Rn[8] * Rs[7];
            float ro22 = Rn[2] * Rs[2] + Rn[5] * Rs[5] + Rn[8] * Rs[8];
            float dist = sqrtf(rel0 * rel0 + rel1 * rel1 + rel2 * rel2);
            half4 f0, f1, f2;
            f0[0] = (_Float16)rr0; f0[1] = (_Float16)rr1; f0[2] = (_Float16)rr2;
            f0[3] = (_Float16)(fast_atan2(ro10, ro00) * INV_PI);
            f1[0] = (_Float16)(fast_asin(clampf(-ro20, -1.f, 1.f)) * INV_PI);
            f1[1] = (_Float16)(fast_atan2(ro21, ro22) * INV_PI);
            f1[2] = (_Float16)dist;                 // |rot_rel| == |rel|
            f1[3] = (_Float16)fast_atan2(rr1, rr0);
            f2[0] = (_Float16)fast_acos(clampf(rr2 * __builtin_amdgcn_rcpf(dist + EPSF), -1.f, 1.f));
            f2[1] = (_Float16)(Rn[0] * vjx + Rn[3] * vjy + Rn[6] * vjz);
            f2[2] = (_Float16)(Rn[1] * vjx + Rn[4] * vjy + Rn[7] * vjz);
            f2[3] = (_Float16)(Rn[2] * vjx + Rn[5] * vjy + Rn[8] * vjz);
            int t = tid >> 4, m = tid & 15;
            half4* dst = eaA + buf * 448 + t * 64;
            dst[m]      = f0;   // k 0..3
            dst[16 + m] = f1;   // k 4..7
            dst[32 + m] = f2;   // k 8..11  (k 12..15 stays zero)
        }
    };

    // ---- pipelined edge phase
    edge_features(0, 0);
    __syncthreads();

#pragma unroll
    for (int g = 0; g < G; ++g) {
        float part[4] = {0.f, 0.f, 0.f, 0.f};
        f32x4 c0, c1, c2, c3;
        {
            float bs0 = baseF[g * 128 + wv * 64 +  0 + lm];
            float bs1 = baseF[g * 128 + wv * 64 + 16 + lm];
            float bs2 = baseF[g * 128 + wv * 64 + 32 + lm];
            float bs3 = baseF[g * 128 + wv * 64 + 48 + lm];
            c0 = (f32x4){bs0, bs0, bs0, bs0};
            c1 = (f32x4){bs1, bs1, bs1, bs1};
            c2 = (f32x4){bs2, bs2, bs2, bs2};
            c3 = (f32x4){bs3, bs3, bs3, bs3};
        }
        const half4* ea = eaA + (g & 1) * 448;
#pragma unroll
        for (int t = 0; t < 6; ++t) {
            half4 a = ea[t * 64 + L];
            f32x4 d0 = __builtin_amdgcn_mfma_f32_16x16x16f16(a, bfr[0], c0, 0, 0, 0);
            f32x4 d1 = __builtin_amdgcn_mfma_f32_16x16x16f16(a, bfr[1], c1, 0, 0, 0);
            f32x4 d2 = __builtin_amdgcn_mfma_f32_16x16x16f16(a, bfr[2], c2, 0, 0, 0);
            f32x4 d3 = __builtin_amdgcn_mfma_f32_16x16x16f16(a, bfr[3], c3, 0, 0, 0);
#pragma unroll
            for (int r = 0; r < 4; ++r) {
                part[0] += d0[r] * fast_sig(d0[r]);
                part[1] += d1[r] * fast_sig(d1[r]);
                part[2] += d2[r] * fast_sig(d2[r]);
                part[3] += d3[r] * fast_sig(d3[r]);
            }
        }
        {   // tail tile: edges 96..98 live (q==0, r<3)
            half4 a = ea[6 * 64 + L];
            f32x4 d0 = __builtin_amdgcn_mfma_f32_16x16x16f16(a, bfr[0], c0, 0, 0, 0);
            f32x4 d1 = __builtin_amdgcn_mfma_f32_16x16x16f16(a, bfr[1], c1, 0, 0, 0);
            f32x4 d2 = __builtin_amdgcn_mfma_f32_16x16x16f16(a, bfr[2], c2, 0, 0, 0);
            f32x4 d3 = __builtin_amdgcn_mfma_f32_16x16x16f16(a, bfr[3], c3, 0, 0, 0);
            bool ok = (q == 0);
#pragma unroll
            for (int r = 0; r < 3; ++r) {
                part[0] += ok ? d0[r] * fast_sig(d0[r]) : 0.f;
                part[1] += ok ? d1[r] * fast_sig(d1[r]) : 0.f;
                part[2] += ok ? d2[r] * fast_sig(d2[r]) : 0.f;
                part[3] += ok ? d3[r] * fast_sig(d3[r]) : 0.f;
            }
        }
        if (g < G - 1) edge_features(g + 1, (g + 1) & 1);   // overlapped producer
#pragma unroll
        for (int i = 0; i < 4; ++i) {
            float v = part[i];
            v += __shfl_xor(v, 16, 64);
            v += __shfl_xor(v, 32, 64);
            if (L < 16) xFp[g * 132 + wv * 64 + i * 16 + L] = v;
        }
        __syncthreads();
    }

    // ---- node MLP: 3 layers, fp16 MFMA (16 MFMA/layer)
#pragma unroll
    for (int layer = 0; layer < 3; ++layer) {
#pragma unroll
        for (int r = 0; r < G; ++r)
            xh[r * XST + tid] = (_Float16)xFp[r * 132 + tid];
        __syncthreads();
        int rowb = (lm & 3) * XST;        // rows 4..15 read dup rows (unread D rows)
        half8 ah[4];
#pragma unroll
        for (int kt = 0; kt < 4; ++kt)
            ah[kt] = *(const half8*)&xh[rowb + kt * 32 + q * 8];
        f32x4 acc[4];
#pragma unroll
        for (int i = 0; i < 4; ++i) acc[i] = (f32x4){0.f, 0.f, 0.f, 0.f};
#pragma unroll
        for (int kt = 0; kt < 4; ++kt) {
            int base = ((layer * 4 + kt) * 8 + wv * 4) * 64 + L;
#pragma unroll
            for (int i = 0; i < 4; ++i) {
                half8 bh = wmlp[base + i * 64];
                acc[i] = __builtin_amdgcn_mfma_f32_16x16x32_f16(ah[kt], bh, acc[i], 0, 0, 0);
            }
        }
        __syncthreads();                  // xh reads done; xF safe to rewrite
        if (L < 16) {                     // quad 0 holds rows 0..3 (the 4 nodes)
#pragma unroll
            for (int i = 0; i < 4; ++i) {
                int ch = wv * 64 + i * 16 + lm;
                if (layer == 0) {
                    float b2c = b2[ch], brc = br[ch];
                    float w3c = Wr[3 * H + ch], w4c = Wr[4 * H + ch], w5c = Wr[5 * H + ch];
#pragma unroll
                    for (int r = 0; r < 4; ++r)
                        xFp[r * 132 + ch] = acc[i][r] * (1.f / 99.f) + b2c
                                          + rmFp[r * 16 + 9] * w3c + rmFp[r * 16 + 10] * w4c
                                          + rmFp[r * 16 + 11] * w5c + brc;
                } else {
                    float bb = (layer == 1) ? b3[ch] : b4[ch];
#pragma unroll
                    for (int r = 0; r < 4; ++r)
                        xFp[r * 132 + ch] = fmaxf(0.f, acc[i][r] + bb);
                }
            }
        }
        __syncthreads();
    }

    // ---- pred = p2 @ W5 + b5, then rotate + residual (pbF/predF alias baseF)
    if (tid < 96) {
        int o = tid >> 4, sl = tid & 15, kb = sl * 8;
        float w5[8];
#pragma unroll
        for (int j = 0; j < 8; ++j) w5[j] = W5[(kb + j) * IN + o];
#pragma unroll
        for (int g = 0; g < G; ++g) {
            float s = 0.f;
#pragma unroll
            for (int j = 0; j < 8; ++j) s = fmaf(xFp[g * 132 + kb + j], w5[j], s);
            pbF[g * 96 + sl * 6 + o] = s;
        }
    }
    __syncthreads();
    if (tid < 24) {
        int g = tid / 6, o = tid - g * 6;
        float s = b5[o];
#pragma unroll
        for (int sl = 0; sl < 16; ++sl) s += pbF[g * 96 + sl * 6 + o];
        predF[g * 8 + o] = s;
    }
    __syncthreads();
    if (tid < 24) {
        int g = tid / 6, o = tid - g * 6;
        int r = (o < 3) ? o : o - 3;
        int off = (o < 3) ? 0 : 3;
        float gl = rmFp[g * 16 + r * 3 + 0] * predF[g * 8 + off + 0]
                 + rmFp[g * 16 + r * 3 + 1] * predF[g * 8 + off + 1]
                 + rmFp[g * 16 + r * 3 + 2] * predF[g * 8 + off + 2];
        int bng = bn0 + g;
        out[bng * IN + o] = in[bng * IN + o] + gl;
    }
}

extern "C" void kernel_launch(void* const* d_in, const int* in_sizes, int n_in,
                              void* d_out, int out_size, void* d_ws, size_t ws_size,
                              hipStream_t stream) {
    const float* in = (const float*)d_in[0];
    const float* W1 = (const float*)d_in[1];
    const float* b1 = (const float*)d_in[2];
    const float* W2 = (const float*)d_in[3];
    const float* b2 = (const float*)d_in[4];
    const float* Wr = (const float*)d_in[5];
    const float* br = (const float*)d_in[6];
    const float* W3 = (const float*)d_in[7];
    const float* b3 = (const float*)d_in[8];
    const float* W4 = (const float*)d_in[9];
    const float* b4 = (const float*)d_in[10];
    const float* W5 = (const float*)d_in[11];
    const float* b5 = (const float*)d_in[12];
    float* out = (float*)d_out;

    half4* w1f  = (half4*)d_ws;                         // 4 KB
    half8* wmlp = (half8*)((char*)d_ws + 4096);         // 96 KB

    const int BN = in_sizes[0] / IN;   // B*N = 12800
    conv_w<<<26, 256, 0, stream>>>(W1, W2, W3, W4, w1f, wmlp);
    locs_fused<<<BN / G, 128, 0, stream>>>(in, W1, b1, b2, Wr, br, b3, b4,
                                           W5, b5, w1f, wmlp, out);
}